// Round 11
// baseline (215.008 us; speedup 1.0000x reference)
//
#include <hip/hip_runtime.h>
#include <math.h>

#define NROWS 8192
#define NCOLS 1000
#define NSLOT 64
#define NEGF  -1.0e30f      // finite "-inf": expf(NEGF*0.05)==0 exactly, no inf*0 NaN
#define NHALF (NROWS * 2)   // 16384 half-rows, one wave each
#define NCOMP 33            // 26 reduced stats + 7 target logits
#define WS_NEEDED (1536u + (size_t)NCOMP * NHALF * 4u)
// ws layout: [0,512) double S1[64] ; [512,1024) double S2[64] ; [1024,1280) unsigned MX[64]
//            [1536, 1536 + NCOMP*NHALF*4) float partials, SoA: part[c*NHALF + wid]

__device__ __forceinline__ unsigned encf(float x) {
    unsigned u = __float_as_uint(x);
    return (u & 0x80000000u) ? ~u : (u | 0x80000000u);
}
__device__ __forceinline__ float decf(unsigned e) {
    unsigned u = (e & 0x80000000u) ? (e ^ 0x80000000u) : ~e;
    return __uint_as_float(u);
}
__device__ __forceinline__ float pick4(const float* a, int k) {
    return k == 0 ? a[0] : (k == 1 ? a[1] : (k == 2 ? a[2] : a[3]));
}

// Phase 1: one wave per HALF-row (cols [h*500, h*500+500)). 2 chunks of
// float4 per lane; 12 loads/wave. 16384 short waves maximize independent
// HBM streams (R4-R9 lesson: one wave per row = 24-load serial chain that
// neither the compiler nor hand asm could hide at ~2-3 waves/SIMD).
// No launch_bounds min-waves hint (suspected residency cap in R6/R7/R9).
__global__ __launch_bounds__(256) void partial_kernel(
    const float* __restrict__ p0, const float* __restrict__ p1,
    const float* __restrict__ p2, const float* __restrict__ p3,
    const float* __restrict__ p4, const float* __restrict__ p5,
    const int* __restrict__ targets, float* __restrict__ part)
{
    const int wid = blockIdx.x * 4 + (threadIdx.x >> 6);   // half-row id
    const int l   = threadIdx.x & 63;
    const int row = wid >> 1;
    const int h   = wid & 1;
    const size_t rbase = (size_t)row * NCOLS;

    // target ownership
    const int tgt = targets[row];
    const int c4t = tgt >> 2;
    const int ht  = (c4t >= 125) ? 1 : 0;
    const int local = c4t - ht * 125;
    const int qt  = (local >= 64) ? 1 : 0;
    const int lt  = qt ? (local - 64) : local;
    const int kt  = tgt & 3;
    const bool own = (h == ht);

    // chunk0: c4 = h*125 + l        (all 64 lanes valid)
    // chunk1: c4 = h*125 + 64 + l   (valid iff l < 61; clamp addr, mask after)
    const int  c40 = h * 125 + l;
    const bool ok1 = (l < 61);
    const int  c41 = h * 125 + (ok1 ? (64 + l) : 124);
    const size_t off0 = rbase + ((size_t)c40 << 2);
    const size_t off1 = rbase + ((size_t)c41 << 2);

    float4 A0 = *(const float4*)(p0 + off0), B0 = *(const float4*)(p0 + off1);
    float4 A1 = *(const float4*)(p1 + off0), B1 = *(const float4*)(p1 + off1);
    float4 A2 = *(const float4*)(p2 + off0), B2 = *(const float4*)(p2 + off1);
    float4 A3 = *(const float4*)(p3 + off0), B3 = *(const float4*)(p3 + off1);
    float4 A4 = *(const float4*)(p4 + off0), B4 = *(const float4*)(p4 + off1);
    float4 A5 = *(const float4*)(p5 + off0), B5 = *(const float4*)(p5 + off1);

    float m1[6], m2[6], zs[6], ds[6];
    #pragma unroll
    for (int s = 0; s < 6; ++s) { m1[s] = NEGF; m2[s] = NEGF; zs[s] = 0.f; ds[s] = 0.f; }
    float z1 = 0.f, z20 = 0.f;
    float sg[7];
    #pragma unroll
    for (int s = 0; s < 7; ++s) sg[s] = 0.f;

    #pragma unroll
    for (int q = 0; q < 2; ++q) {
        float v[7][4];   // [0..4]=teachers, [5]=mimic, [6]=out_s
        if (q == 0) {
            v[0][0]=A0.x; v[0][1]=A0.y; v[0][2]=A0.z; v[0][3]=A0.w;
            v[1][0]=A1.x; v[1][1]=A1.y; v[1][2]=A1.z; v[1][3]=A1.w;
            v[2][0]=A2.x; v[2][1]=A2.y; v[2][2]=A2.z; v[2][3]=A2.w;
            v[3][0]=A3.x; v[3][1]=A3.y; v[3][2]=A3.z; v[3][3]=A3.w;
            v[4][0]=A4.x; v[4][1]=A4.y; v[4][2]=A4.z; v[4][3]=A4.w;
            v[6][0]=A5.x; v[6][1]=A5.y; v[6][2]=A5.z; v[6][3]=A5.w;
        } else {
            v[0][0]=B0.x; v[0][1]=B0.y; v[0][2]=B0.z; v[0][3]=B0.w;
            v[1][0]=B1.x; v[1][1]=B1.y; v[1][2]=B1.z; v[1][3]=B1.w;
            v[2][0]=B2.x; v[2][1]=B2.y; v[2][2]=B2.z; v[2][3]=B2.w;
            v[3][0]=B3.x; v[3][1]=B3.y; v[3][2]=B3.z; v[3][3]=B3.w;
            v[4][0]=B4.x; v[4][1]=B4.y; v[4][2]=B4.z; v[4][3]=B4.w;
            v[6][0]=B5.x; v[6][1]=B5.y; v[6][2]=B5.z; v[6][3]=B5.w;
        }
        const bool pad = (q == 1) && !ok1;
        if (pad) {
            #pragma unroll
            for (int s = 0; s < 7; ++s)
                #pragma unroll
                for (int k = 0; k < 4; ++k) v[s][k] = NEGF;
        }
        #pragma unroll
        for (int k = 0; k < 4; ++k)
            v[5][k] = (v[0][k] + v[1][k] + v[2][k] + v[3][k] + v[4][k]) * 0.2f;
        if (pad) {
            #pragma unroll
            for (int k = 0; k < 4; ++k) v[5][k] = NEGF;
        }

        #pragma unroll
        for (int s = 0; s < 6; ++s) {
            float a = v[s][0], b = v[s][1], c = v[s][2], d = v[s][3];
            float hi1 = fmaxf(a, b), lo1 = fminf(a, b);
            float hi2 = fmaxf(c, d), lo2 = fminf(c, d);
            float q1 = fmaxf(hi1, hi2);
            float q2 = fmaxf(fminf(hi1, hi2), fmaxf(lo1, lo2));
            float nm1 = fmaxf(m1[s], q1);
            float nm2 = fmaxf(fminf(m1[s], q1), fmaxf(m2[s], q2));
            m1[s] = nm1; m2[s] = nm2;
            float zz = 0.f, dot = 0.f;
            #pragma unroll
            for (int k = 0; k < 4; ++k) {
                float e = __expf(v[s][k] * 0.05f);    // ==0 exactly for padding
                zz += e; dot += e * v[6][k];
            }
            zs[s] += zz; ds[s] += dot;
        }
        #pragma unroll
        for (int k = 0; k < 4; ++k) {
            z1  += __expf(v[6][k]);
            z20 += __expf(v[6][k] * 0.05f);
        }
        if (own && q == qt && l == lt) {
            #pragma unroll
            for (int s = 0; s < 7; ++s) sg[s] = pick4(v[s], kt);
        }
    }

    // in-wave butterfly over the 26 reducible stats
    #pragma unroll
    for (int xm = 1; xm < 64; xm <<= 1) {
        #pragma unroll
        for (int s = 0; s < 6; ++s) {
            float o1 = __shfl_xor(m1[s], xm);
            float o2 = __shfl_xor(m2[s], xm);
            float nm1 = fmaxf(m1[s], o1);
            float nm2 = fmaxf(fminf(m1[s], o1), fmaxf(m2[s], o2));
            m1[s] = nm1; m2[s] = nm2;
            zs[s] += __shfl_xor(zs[s], xm);
            ds[s] += __shfl_xor(ds[s], xm);
        }
        z1  += __shfl_xor(z1, xm);
        z20 += __shfl_xor(z20, xm);
    }

    // SoA store: component c at part[c*NHALF + wid] (phase-2 reads coalesce)
    if (l == 0) {
        #pragma unroll
        for (int s = 0; s < 6; ++s) {
            part[(0  + s) * NHALF + wid] = m1[s];
            part[(6  + s) * NHALF + wid] = m2[s];
            part[(12 + s) * NHALF + wid] = zs[s];
            part[(18 + s) * NHALF + wid] = ds[s];
        }
        part[24 * NHALF + wid] = z1;
        part[25 * NHALF + wid] = z20;
    }
    if (own && l == lt) {
        #pragma unroll
        for (int s = 0; s < 7; ++s)
            part[(26 + s) * NHALF + wid] = sg[s];
    }
}

// Phase 2: one THREAD per row. Merge the two half-row partials, run the
// epilogue, accumulate into 64 slots (consecutive threads -> distinct slots).
__global__ __launch_bounds__(256) void merge_kernel(
    const float* __restrict__ part, const int* __restrict__ targets,
    double* __restrict__ S1, double* __restrict__ S2, unsigned* __restrict__ MX)
{
    const int row = blockIdx.x * 256 + threadIdx.x;
    const int w0 = row * 2, w1 = w0 + 1;

    float m1[6], m2[6], zs[6], ds[6];
    #pragma unroll
    for (int s = 0; s < 6; ++s) {
        float a1 = part[(0 + s) * NHALF + w0], b1 = part[(0 + s) * NHALF + w1];
        float a2 = part[(6 + s) * NHALF + w0], b2 = part[(6 + s) * NHALF + w1];
        m1[s] = fmaxf(a1, b1);
        m2[s] = fmaxf(fminf(a1, b1), fmaxf(a2, b2));
        zs[s] = part[(12 + s) * NHALF + w0] + part[(12 + s) * NHALF + w1];
        ds[s] = part[(18 + s) * NHALF + w0] + part[(18 + s) * NHALF + w1];
    }
    const float z1  = part[24 * NHALF + w0] + part[24 * NHALF + w1];
    const float z20 = part[25 * NHALF + w0] + part[25 * NHALF + w1];

    const int tgt = targets[row];
    const int wo  = ((tgt >> 2) >= 125) ? w1 : w0;   // owner half-row record
    float sgv[7];
    #pragma unroll
    for (int s = 0; s < 7; ++s) sgv[s] = part[(26 + s) * NHALF + wo];

    const float lse1  = logf(z1);
    const float lse20 = logf(z20);
    const float CE    = lse1 - sgv[6];

    float KD[6], mg[6];
    float mmax = 0.f;   // margins >= 0 always
    #pragma unroll
    for (int s = 0; s < 6; ++s) {
        KD[s] = 400.f * lse20 - 20.f * (ds[s] / zs[s]);
        mg[s] = (sgv[s] == m1[s]) ? (m1[s] - m2[s]) : 0.f;
        mmax  = fmaxf(mmax, mg[s]);
    }
    float es[6], se = 0.f;
    #pragma unroll
    for (int s = 0; s < 6; ++s) { es[s] = __expf((mg[s] - mmax) * 0.5f); se += es[s]; }

    double rS2 = 0.0;
    #pragma unroll
    for (int s = 0; s < 6; ++s)
        rS2 += (double)(es[s] / se) * (double)sgv[s] * (double)(KD[s] - CE);

    float tmax = fmaxf(fmaxf(fmaxf(m1[0], m1[1]), fmaxf(m1[2], m1[3])), m1[4]);
    atomicAdd(&S1[row & (NSLOT - 1)], (double)CE);
    atomicAdd(&S2[row & (NSLOT - 1)], rS2);
    atomicMax(&MX[row & (NSLOT - 1)], encf(tmax));
}

// ---- Fallback path (R6, known-good 84us): one wave per row, 4 waves/block,
// needs only the 1280B slot region of ws. Used only if ws_size < WS_NEEDED.
__global__ __launch_bounds__(256, 4) void row_kernel_fb(
    const float* __restrict__ p0, const float* __restrict__ p1,
    const float* __restrict__ p2, const float* __restrict__ p3,
    const float* __restrict__ p4, const float* __restrict__ p5,
    const int* __restrict__ targets,
    double* __restrict__ S1, double* __restrict__ S2, unsigned* __restrict__ MX)
{
    const int wave = threadIdx.x >> 6;
    const int l    = threadIdx.x & 63;
    const int row  = blockIdx.x * 4 + wave;

    const int tgt = targets[row];
    const int t4  = tgt >> 2;
    const int lt  = t4 & 63;
    const int qt  = t4 >> 6;
    const int kt  = tgt & 3;

    float m1[6], m2[6], zs[6], ds[6];
    #pragma unroll
    for (int s = 0; s < 6; ++s) { m1[s] = NEGF; m2[s] = NEGF; zs[s] = 0.f; ds[s] = 0.f; }
    float z1 = 0.f, z20 = 0.f;
    float sg[7];
    #pragma unroll
    for (int s = 0; s < 7; ++s) sg[s] = 0.f;

    #pragma unroll 2
    for (int q = 0; q < 4; ++q) {
        const int  c4 = l + (q << 6);
        const bool ok = (c4 < (NCOLS >> 2));
        const size_t base = (size_t)row * NCOLS + ((size_t)c4 << 2);

        float v[7][4];
        if (ok) {
            float4 x0 = *(const float4*)(p0 + base);
            float4 x1 = *(const float4*)(p1 + base);
            float4 x2 = *(const float4*)(p2 + base);
            float4 x3 = *(const float4*)(p3 + base);
            float4 x4 = *(const float4*)(p4 + base);
            float4 x5 = *(const float4*)(p5 + base);
            v[0][0]=x0.x; v[0][1]=x0.y; v[0][2]=x0.z; v[0][3]=x0.w;
            v[1][0]=x1.x; v[1][1]=x1.y; v[1][2]=x1.z; v[1][3]=x1.w;
            v[2][0]=x2.x; v[2][1]=x2.y; v[2][2]=x2.z; v[2][3]=x2.w;
            v[3][0]=x3.x; v[3][1]=x3.y; v[3][2]=x3.z; v[3][3]=x3.w;
            v[4][0]=x4.x; v[4][1]=x4.y; v[4][2]=x4.z; v[4][3]=x4.w;
            v[6][0]=x5.x; v[6][1]=x5.y; v[6][2]=x5.z; v[6][3]=x5.w;
            #pragma unroll
            for (int k = 0; k < 4; ++k)
                v[5][k] = (v[0][k] + v[1][k] + v[2][k] + v[3][k] + v[4][k]) * 0.2f;
        } else {
            #pragma unroll
            for (int s = 0; s < 7; ++s)
                #pragma unroll
                for (int k = 0; k < 4; ++k) v[s][k] = NEGF;
        }

        #pragma unroll
        for (int s = 0; s < 6; ++s) {
            float a = v[s][0], b = v[s][1], c = v[s][2], d = v[s][3];
            float hi1 = fmaxf(a, b), lo1 = fminf(a, b);
            float hi2 = fmaxf(c, d), lo2 = fminf(c, d);
            float q1 = fmaxf(hi1, hi2);
            float q2 = fmaxf(fminf(hi1, hi2), fmaxf(lo1, lo2));
            float nm1 = fmaxf(m1[s], q1);
            float nm2 = fmaxf(fminf(m1[s], q1), fmaxf(m2[s], q2));
            m1[s] = nm1; m2[s] = nm2;
            float zz = 0.f, dot = 0.f;
            #pragma unroll
            for (int k = 0; k < 4; ++k) {
                float e = __expf(v[s][k] * 0.05f);
                zz += e; dot += e * v[6][k];
            }
            zs[s] += zz; ds[s] += dot;
        }
        #pragma unroll
        for (int k = 0; k < 4; ++k) {
            z1  += __expf(v[6][k]);
            z20 += __expf(v[6][k] * 0.05f);
        }
        if (ok && q == qt && l == lt) {
            #pragma unroll
            for (int s = 0; s < 7; ++s) sg[s] = pick4(v[s], kt);
        }
    }

    #pragma unroll
    for (int xm = 1; xm < 64; xm <<= 1) {
        #pragma unroll
        for (int s = 0; s < 6; ++s) {
            float o1 = __shfl_xor(m1[s], xm);
            float o2 = __shfl_xor(m2[s], xm);
            float nm1 = fmaxf(m1[s], o1);
            float nm2 = fmaxf(fminf(m1[s], o1), fmaxf(m2[s], o2));
            m1[s] = nm1; m2[s] = nm2;
            zs[s] += __shfl_xor(zs[s], xm);
            ds[s] += __shfl_xor(ds[s], xm);
        }
        z1  += __shfl_xor(z1, xm);
        z20 += __shfl_xor(z20, xm);
    }
    float sgv[7];
    #pragma unroll
    for (int s = 0; s < 7; ++s) sgv[s] = __shfl(sg[s], lt);

    if (l == 0) {
        const float lse1  = logf(z1);
        const float lse20 = logf(z20);
        const float CE    = lse1 - sgv[6];

        float KD[6], mg[6];
        float mmax = 0.f;
        #pragma unroll
        for (int s = 0; s < 6; ++s) {
            KD[s] = 400.f * lse20 - 20.f * (ds[s] / zs[s]);
            mg[s] = (sgv[s] == m1[s]) ? (m1[s] - m2[s]) : 0.f;
            mmax  = fmaxf(mmax, mg[s]);
        }
        float es[6], se = 0.f;
        #pragma unroll
        for (int s = 0; s < 6; ++s) { es[s] = __expf((mg[s] - mmax) * 0.5f); se += es[s]; }

        double rS2 = 0.0;
        #pragma unroll
        for (int s = 0; s < 6; ++s)
            rS2 += (double)(es[s] / se) * (double)sgv[s] * (double)(KD[s] - CE);

        float tmax = fmaxf(fmaxf(fmaxf(m1[0], m1[1]), fmaxf(m1[2], m1[3])), m1[4]);
        atomicAdd(&S1[row & (NSLOT - 1)], (double)CE);
        atomicAdd(&S2[row & (NSLOT - 1)], rS2);
        atomicMax(&MX[row & (NSLOT - 1)], encf(tmax));
    }
}

__global__ void final_kernel(const double* __restrict__ S1, const double* __restrict__ S2,
                             const unsigned* __restrict__ MX, float* __restrict__ out)
{
    const int tid = threadIdx.x;  // 64 threads
    double s1 = S1[tid], s2 = S2[tid];
    unsigned m = MX[tid];
    #pragma unroll
    for (int k = 32; k >= 1; k >>= 1) {
        s1 += __shfl_xor(s1, k);
        s2 += __shfl_xor(s2, k);
        unsigned om = __shfl_xor(m, k);
        m = (om > m) ? om : m;
    }
    if (tid == 0) {
        double maxp = (double)decf(m);
        out[0] = (float)((s1 + (0.8 / maxp) * s2) / (double)NROWS);
    }
}

extern "C" void kernel_launch(void* const* d_in, const int* in_sizes, int n_in,
                              void* d_out, int out_size, void* d_ws, size_t ws_size,
                              hipStream_t stream)
{
    const float* t1 = (const float*)d_in[0];
    const float* t2 = (const float*)d_in[1];
    const float* t3 = (const float*)d_in[2];
    const float* t4 = (const float*)d_in[3];
    const float* t5 = (const float*)d_in[4];
    const float* os = (const float*)d_in[5];
    const int* targets = (const int*)d_in[6];

    double*   S1   = (double*)d_ws;
    double*   S2   = S1 + NSLOT;
    unsigned* MX   = (unsigned*)(S2 + NSLOT);
    float*    part = (float*)((char*)d_ws + 1536);   // NCOMP*NHALF*4 ~ 2.07 MiB

    hipMemsetAsync(d_ws, 0, NSLOT * (8 + 8 + 4), stream);
    if (ws_size >= WS_NEEDED) {
        partial_kernel<<<NHALF / 4, 256, 0, stream>>>(t1, t2, t3, t4, t5, os, targets, part);
        merge_kernel<<<NROWS / 256, 256, 0, stream>>>(part, targets, S1, S2, MX);
    } else {
        row_kernel_fb<<<NROWS / 4, 256, 0, stream>>>(t1, t2, t3, t4, t5, os, targets, S1, S2, MX);
    }
    final_kernel<<<1, 64, 0, stream>>>(S1, S2, MX, (float*)d_out);
}